// Round 10
// baseline (490.587 us; speedup 1.0000x reference)
//
#include <hip/hip_runtime.h>
#include <cstdint>

// Problem constants (from reference)
constexpr int G = 4, N = 50000, E = 800000;
constexpr int FIN = 64, HID = 128, FOUT = 64;
constexpr int NB = (N + 1023) / 1024;  // scan blocks per graph = 49

// Radix CSR-build parameters (R9)
constexpr int PB = 64;               // partition blocks per graph
constexpr int CP = E / PB;           // 12500 edges per partition chunk (exact)
constexpr int NBK = (N + 255) / 256; // 196 dst-buckets of 256 nodes

typedef unsigned short ushort;
typedef _Float16 f16;

__device__ __forceinline__ ushort f2h(float f) {  // v_cvt_f16_f32 (RNE)
  f16 h = (f16)f;
  return __builtin_bit_cast(ushort, h);
}
__device__ __forceinline__ float h2f(ushort u) {  // v_cvt_f32_f16
  f16 h = __builtin_bit_cast(f16, u);
  return (float)h;
}

// XCD-confined swizzle: block b -> XCD (b&7), 2 XCDs per graph.
// Requires G*N/4 = 50000 blocks; per graph 12500 chunks of 4 nodes.
__device__ __forceinline__ void xcd_map(int b, int& g, int& chunk) {
  int xcd = b & 7;
  int sub = b >> 3;  // 0..6249
  g = xcd >> 1;
  chunk = (xcd & 1) * 6250 + sub;  // 0..12499
}

// ---------------- fp32 -> fp16 conversion of x, PRE-SCALED by dinv ----------------
// R7: fp16 halves gather bytes + L2 working set. R10: also fold dinv[s] into
// the stored row (xh[s] = dinv[s]*x[s]) so the aggregation needs NO per-edge
// dinv gather -- Z = dinv[d] * sum_{s in N(d)+self} xh[s]. Runs AFTER the scans.
__global__ void k_x2h(const float4* __restrict__ X, const float* __restrict__ dinv,
                      ushort4* __restrict__ Xh, int n4) {
  int i = blockIdx.x * blockDim.x + threadIdx.x;
  if (i >= n4) return;
  float sc = dinv[i >> 4];  // 16 float4 per 64-wide row; same dinv for all 16
  float4 v = X[i];
  ushort4 o = {f2h(sc * v.x), f2h(sc * v.y), f2h(sc * v.z), f2h(sc * v.w)};
  Xh[i] = o;
}

// ---------------- CSR build: two-pass radix partition by dst (R9) ----------------
// R8 post-mortem: scattered SUB-LINE stores cost like atomics (8x write amp).
// All global writes made (near-)line-contiguous via 196-bucket dst partition.

// PH[g][k][pb]: bucket-k count of partition chunk pb
__global__ __launch_bounds__(256) void k_phist(const int* __restrict__ ei,
                                               int* __restrict__ PH) {
  __shared__ int h[NBK];
  int pb = blockIdx.x, g = blockIdx.y;
  for (int i = threadIdx.x; i < NBK; i += 256) h[i] = 0;
  __syncthreads();
  const int4* dst4 = (const int4*)(ei + (size_t)g * 2 * E + E + (size_t)pb * CP);
  for (int i = threadIdx.x; i < CP / 4; i += 256) {
    int4 d = dst4[i];
    atomicAdd(&h[d.x >> 8], 1);
    atomicAdd(&h[d.y >> 8], 1);
    atomicAdd(&h[d.z >> 8], 1);
    atomicAdd(&h[d.w >> 8], 1);
  }
  __syncthreads();
  for (int i = threadIdx.x; i < NBK; i += 256)
    PH[((size_t)g * NBK + i) * PB + pb] = h[i];
}

// scan PH -> POFF[g][k][pb] (segment base in pairs) and BB[g][k] (bucket base)
__global__ void k_pscan(const int* __restrict__ PH, int* __restrict__ POFF,
                        int* __restrict__ BB) {
  int g = blockIdx.x, k = threadIdx.x;  // 256 threads, k < NBK active
  int tot = 0;
  if (k < NBK) {
#pragma unroll 8
    for (int pb = 0; pb < PB; ++pb) tot += PH[((size_t)g * NBK + k) * PB + pb];
  }
  __shared__ int sm[256];
  sm[k] = tot;
  __syncthreads();
  for (int off = 1; off < 256; off <<= 1) {
    int v = (k >= off) ? sm[k - off] : 0;
    __syncthreads();
    sm[k] += v;
    __syncthreads();
  }
  int excl = sm[k] - tot;
  if (k < NBK) {
    BB[g * (NBK + 1) + k] = excl;
    if (k == NBK - 1) BB[g * (NBK + 1) + NBK] = excl + tot;  // == E
    int run = excl;
#pragma unroll 8
    for (int pb = 0; pb < PB; ++pb) {
      POFF[((size_t)g * NBK + k) * PB + pb] = run;
      run += PH[((size_t)g * NBK + k) * PB + pb];
    }
  }
}

// partition: write packed (src, dst&255) into bucket-major pairs array
__global__ __launch_bounds__(256) void k_part(const int* __restrict__ ei,
                                              const int* __restrict__ POFF,
                                              unsigned* __restrict__ pairs) {
  __shared__ int off[NBK];
  __shared__ int rk[NBK];
  int pb = blockIdx.x, g = blockIdx.y;
  for (int i = threadIdx.x; i < NBK; i += 256) {
    off[i] = POFF[((size_t)g * NBK + i) * PB + pb];
    rk[i] = 0;
  }
  __syncthreads();
  const int* base = ei + (size_t)g * 2 * E + (size_t)pb * CP;
  const int4* s4 = (const int4*)base;
  const int4* d4 = (const int4*)(base + E);
  unsigned* pg = pairs + (size_t)g * E;
  for (int i = threadIdx.x; i < CP / 4; i += 256) {
    int4 s = s4[i], d = d4[i];
    int sv[4] = {s.x, s.y, s.z, s.w};
    int dv[4] = {d.x, d.y, d.z, d.w};
#pragma unroll
    for (int k = 0; k < 4; ++k) {
      int b = dv[k] >> 8;
      int r = atomicAdd(&rk[b], 1);
      pg[off[b] + r] = (unsigned)sv[k] | ((unsigned)(dv[k] & 255) << 16);
    }
  }
}

// per-bucket exact node counts -> cnt (contiguous writes)
__global__ __launch_bounds__(256) void k_bcnt(const unsigned* __restrict__ pairs,
                                              const int* __restrict__ BB,
                                              int* __restrict__ cnt) {
  __shared__ int h[256];
  int k = blockIdx.x, g = blockIdx.y;
  h[threadIdx.x] = 0;
  __syncthreads();
  int lo = BB[g * (NBK + 1) + k], hi = BB[g * (NBK + 1) + k + 1];
  const unsigned* pg = pairs + (size_t)g * E;
  for (int i = lo + (int)threadIdx.x; i < hi; i += 256)
    atomicAdd(&h[(pg[i] >> 16) & 255], 1);
  __syncthreads();
  int n0 = k << 8;
  int nn = min(256, N - n0);
  if ((int)threadIdx.x < nn) cnt[g * N + n0 + threadIdx.x] = h[threadIdx.x];
}

// place srcs into col; scatter confined to the bucket's ~16KB col window
__global__ __launch_bounds__(256) void k_place(const unsigned* __restrict__ pairs,
                                               const int* __restrict__ BB,
                                               const int* __restrict__ rowptr,
                                               int* __restrict__ col) {
  __shared__ int rp[256];
  __shared__ int rk[256];
  int k = blockIdx.x, g = blockIdx.y;
  int n0 = k << 8;
  int nn = min(256, N - n0);
  if ((int)threadIdx.x < nn) rp[threadIdx.x] = rowptr[g * (N + 1) + n0 + threadIdx.x];
  rk[threadIdx.x] = 0;
  __syncthreads();
  int lo = BB[g * (NBK + 1) + k], hi = BB[g * (NBK + 1) + k + 1];
  const unsigned* pg = pairs + (size_t)g * E;
  int* cg = col + (size_t)g * E;
  for (int i = lo + (int)threadIdx.x; i < hi; i += 256) {
    unsigned p = pg[i];
    int dl = (p >> 16) & 255;
    int r = atomicAdd(&rk[dl], 1);
    cg[rp[dl] + r] = (int)(p & 0xffffu);
  }
}

// ---- 3-kernel exclusive scan of cnt -> rowptr (per graph) ----
__global__ void k_scan_partial(const int* __restrict__ cnt, int* __restrict__ part) {
  int g = blockIdx.y, b = blockIdx.x, tid = threadIdx.x;
  int base = b * 1024 + tid * 4;
  int s = 0;
#pragma unroll
  for (int k = 0; k < 4; ++k) {
    int i = base + k;
    if (i < N) s += cnt[g * N + i];
  }
  __shared__ int sm[256];
  sm[tid] = s;
  __syncthreads();
  for (int off = 128; off > 0; off >>= 1) {
    if (tid < off) sm[tid] += sm[tid + off];
    __syncthreads();
  }
  if (tid == 0) part[g * NB + b] = sm[0];
}

__global__ void k_scan_mid(int* __restrict__ part, int* __restrict__ rowptr) {
  int g = blockIdx.x;
  if (threadIdx.x != 0) return;
  int run = 0;
  for (int b = 0; b < NB; ++b) {
    int t = part[g * NB + b];
    part[g * NB + b] = run;
    run += t;
  }
  rowptr[g * (N + 1) + N] = run;  // == E
}

// final scan + fused dinv computation
__global__ void k_scan_final(const int* __restrict__ cnt, const int* __restrict__ part,
                             int* __restrict__ rowptr, float* __restrict__ dinv) {
  int g = blockIdx.y, b = blockIdx.x, tid = threadIdx.x;
  int base = b * 1024 + tid * 4;
  int c[4];
  int s = 0;
#pragma unroll
  for (int k = 0; k < 4; ++k) {
    int i = base + k;
    c[k] = (i < N) ? cnt[g * N + i] : 0;
    s += c[k];
  }
  __shared__ int sm[256];
  sm[tid] = s;
  __syncthreads();
  for (int off = 1; off < 256; off <<= 1) {
    int v = (tid >= off) ? sm[tid - off] : 0;
    __syncthreads();
    sm[tid] += v;
    __syncthreads();
  }
  int excl = sm[tid] - s + part[g * NB + b];
#pragma unroll
  for (int k = 0; k < 4; ++k) {
    int i = base + k;
    if (i < N) {
      rowptr[g * (N + 1) + i] = excl;
      dinv[g * N + i] = rsqrtf((float)(c[k] + 1));  // +1 self loop
    }
    excl += c[k];
  }
}

// ---------------- fused MLP: h2s = dinv * (ELU(Z@W1 + b1) @ W2), fp16 out ----------------
// R14: R13's two-phase LDS partial-reduce (33KB LDS -> 4 blk/CU, 5 barriers,
// 46% idle, 129us vs 42us FMA floor) restructured: gemm1 k-slices are written
// to LDS as PACKED FP16 h1 [64][130] (16.64KB == x-tile size -> union buffer),
// then gemm2 reads full h1 rows (wave w computes cols [16w,16w+16), lane=row).
// 3 barriers, no partial reduce; 16.64KB LDS -> 8 blk/CU (wave-capped, 100%).
// __launch_bounds__(256,8) pins VGPR<=64 (acc[32]/acc2[16] live ranges split).
// W1/W2 addresses scalar (readfirstlane) -> constant-cache s_load (R5 lesson).
// h1s bank map: dword idx = row*65 + c/2 -> (row + c/2)%32, 2 lanes/bank, free.
__global__ __launch_bounds__(256, 8) void k_mlp(const float* __restrict__ X,
                                                const float* __restrict__ W1,
                                                const float* __restrict__ b1,
                                                const float* __restrict__ W2,
                                                const float* __restrict__ dinv,
                                                ushort* __restrict__ H2s) {
  constexpr int K = FIN;     // 64
  constexpr int PK = K + 1;  // padded x-tile row stride
  __shared__ float lds[64 * PK];        // 16640B; aliased as fp16 h1 [64][130]
  ushort* h1s = (ushort*)lds;
  int g = blockIdx.y;
  int R0 = blockIdx.x * 64;
  // stage 64 rows of Z (coalesced global read, conflict-free LDS write)
  for (int idx = threadIdx.x; idx < 64 * K; idx += 256) {
    int r = idx >> 6, k = idx & 63;
    int row = R0 + r;
    lds[r * PK + k] = (row < N) ? X[((size_t)g * N + row) * K + k] : 0.f;
  }
  __syncthreads();
  int wv = threadIdx.x >> 6;
  int lane = threadIdx.x & 63;
  int c0 = __builtin_amdgcn_readfirstlane(wv * 32);  // SGPR col base (HID slice)
  const float* W1g = W1 + (size_t)g * K * HID;
  const float* xrow = &lds[lane * PK];
  float acc[32];
#pragma unroll
  for (int c = 0; c < 32; ++c) acc[c] = 0.f;
#pragma unroll 4
  for (int k = 0; k < K; ++k) {
    float xv = xrow[k];
#pragma unroll
    for (int c = 0; c < 32; ++c)
      acc[c] = fmaf(xv, W1g[(size_t)k * HID + c0 + c], acc[c]);
  }
  // bias + ELU -> acc = h1[row][c0..c0+31]
#pragma unroll
  for (int c = 0; c < 32; ++c) {
    float v = acc[c] + b1[g * HID + c0 + c];
    acc[c] = v > 0.f ? v : expm1f(v);
  }
  __syncthreads();  // all x-tile reads complete before h1 overwrites the buffer
  // write h1 slice as packed fp16 (dword-aligned, 2-lanes/bank)
#pragma unroll
  for (int c2 = 0; c2 < 16; ++c2) {
    unsigned pk = (unsigned)f2h(acc[2 * c2]) | ((unsigned)f2h(acc[2 * c2 + 1]) << 16);
    *(unsigned*)&h1s[lane * 130 + c0 + 2 * c2] = pk;
  }
  __syncthreads();
  // gemm2: wave w computes output cols [16w, 16w+16) for all 64 rows (lane=row)
  int j0 = __builtin_amdgcn_readfirstlane(wv * 16);
  const float* W2g = W2 + (size_t)g * HID * FOUT + j0;
  float acc2[16];
#pragma unroll
  for (int j = 0; j < 16; ++j) acc2[j] = 0.f;
#pragma unroll 4
  for (int c = 0; c < HID; c += 2) {
    unsigned pk = *(const unsigned*)&h1s[lane * 130 + c];
    float f0 = h2f((ushort)(pk & 0xffffu));
    float f1 = h2f((ushort)(pk >> 16));
    const float* w0 = &W2g[(size_t)c * FOUT];
    const float* w1 = &W2g[(size_t)(c + 1) * FOUT];
#pragma unroll
    for (int j = 0; j < 16; ++j) acc2[j] = fmaf(f0, w0[j], acc2[j]);
#pragma unroll
    for (int j = 0; j < 16; ++j) acc2[j] = fmaf(f1, w1[j], acc2[j]);
  }
  int row = R0 + lane;
  if (row < N) {
    float dd = dinv[g * N + row];
    ushort o[16];
#pragma unroll
    for (int j = 0; j < 16; ++j) o[j] = f2h(acc2[j] * dd);
    ushort* dst = H2s + ((size_t)g * N + row) * FOUT + j0;
    *(uint4*)dst = *(uint4*)&o[0];        // 16B aligned: (row*128 + j0*2) % 16 == 0
    *(uint4*)(dst + 8) = *(uint4*)&o[8];
  }
}

// ---------------- aggregate core (R12) ----------------
// R11 post-mortem: quarter-wave ushort4 gathers REGRESSED -- shfl epilogue
// added 17.9M LDS bank-conflict cycles. R12: R10 scalar-index structure,
// 16-deep primary batch, 8-deep secondary, scalar tail. ~89us floor = TA/
// line-processing bound (2 lines per 128B row-gather), invariant to MLP.
__device__ __forceinline__ float agg_row(const ushort* __restrict__ hb,
                                         const int* __restrict__ cl, int rs, int re,
                                         int lane, float acc) {
  int j = rs;
  for (; j + 16 <= re; j += 16) {
    int s[16];
#pragma unroll
    for (int k = 0; k < 16; ++k) s[k] = cl[j + k];  // uniform -> s_load x16
    float v[16];
#pragma unroll
    for (int k = 0; k < 16; ++k) v[k] = h2f(hb[(size_t)s[k] * 64 + lane]);
#pragma unroll
    for (int k = 0; k < 16; ++k) acc += v[k];
  }
  for (; j + 8 <= re; j += 8) {
    int s[8];
#pragma unroll
    for (int k = 0; k < 8; ++k) s[k] = cl[j + k];
    float v[8];
#pragma unroll
    for (int k = 0; k < 8; ++k) v[k] = h2f(hb[(size_t)s[k] * 64 + lane]);
#pragma unroll
    for (int k = 0; k < 8; ++k) acc += v[k];
  }
  for (; j < re; ++j) acc += h2f(hb[(size_t)cl[j] * 64 + lane]);
  return acc;
}

// layer 1: Z = dinv[d] * sum xh[s] (xh pre-scaled by dinv[s])
template <int F>
__global__ __launch_bounds__(256) void k_agg_in(const ushort* __restrict__ Xh,
                                                const int* __restrict__ rowptr,
                                                const int* __restrict__ col,
                                                const float* __restrict__ dinv,
                                                float* __restrict__ Z) {
  int g, chunk;
  xcd_map(blockIdx.x, g, chunk);
  int d = __builtin_amdgcn_readfirstlane(chunk * 4 + (threadIdx.x >> 6));
  int lane = threadIdx.x & 63;
  const ushort* hb = Xh + (size_t)g * N * F;
  const int* cl = col + (size_t)g * E;
  int rs = rowptr[g * (N + 1) + d];
  int re = rowptr[g * (N + 1) + d + 1];
  float acc = h2f(hb[(size_t)d * F + lane]);  // self loop (pre-scaled row)
  acc = agg_row(hb, cl, rs, re, lane, acc);
  Z[((size_t)g * N + d) * F + lane] = dinv[g * N + d] * acc;
}

// layer 2: out = ELU(dinv[d]*(sum h2s) + b); h2s pre-scaled by dinv[s]
template <int F>
__global__ __launch_bounds__(256) void k_agg_out(const ushort* __restrict__ Hsrc,
                                                 const int* __restrict__ rowptr,
                                                 const int* __restrict__ col,
                                                 const float* __restrict__ dinv,
                                                 const float* __restrict__ bias,
                                                 float* __restrict__ out) {
  int g, chunk;
  xcd_map(blockIdx.x, g, chunk);
  int d = __builtin_amdgcn_readfirstlane(chunk * 4 + (threadIdx.x >> 6));
  int lane = threadIdx.x & 63;
  const ushort* hb = Hsrc + (size_t)g * N * F;
  const int* cl = col + (size_t)g * E;
  int rs = rowptr[g * (N + 1) + d];
  int re = rowptr[g * (N + 1) + d + 1];
  float acc = h2f(hb[(size_t)d * F + lane]);  // self loop
  acc = agg_row(hb, cl, rs, re, lane, acc);
  float p = acc * dinv[g * N + d] + bias[g * F + lane];
  p = p > 0.f ? p : expm1f(p);
  out[((size_t)g * N + d) * F + lane] = p;
}

extern "C" void kernel_launch(void* const* d_in, const int* in_sizes, int n_in,
                              void* d_out, int out_size, void* d_ws, size_t ws_size,
                              hipStream_t stream) {
  const float* x = (const float*)d_in[0];
  const int* ei = (const int*)d_in[1];
  const float* W1 = (const float*)d_in[2];
  const float* b1 = (const float*)d_in[3];
  const float* W2 = (const float*)d_in[4];
  const float* b2 = (const float*)d_in[5];
  float* out = (float*)d_out;

  // Workspace carve-up (layout kept from R9; h1's region now only holds the
  // radix + fp16-x scratch -- h1 itself no longer exists, R13 fused it away)
  char* p = (char*)d_ws;
  auto alloc = [&](size_t bytes) {
    char* r = p;
    p += (bytes + 255) & ~(size_t)255;
    return r;
  };
  int* cnt = (int*)alloc(sizeof(int) * G * N);
  int* rowptr = (int*)alloc(sizeof(int) * G * (N + 1));
  int* part = (int*)alloc(sizeof(int) * G * NB);
  float* dinv = (float*)alloc(sizeof(float) * G * N);
  int* col = (int*)alloc(sizeof(int) * (size_t)G * E);             // 12.8 MB
  float* z = (float*)alloc(sizeof(float) * (size_t)G * N * FIN);   // 51.2 MB
  char* scratch = (char*)alloc((size_t)103 << 20);                 // ex-h1 region
  ushort* h2s = (ushort*)z;  // fp16, 25.6 MB; reuses z (dead after k_mlp reads it)
  unsigned* pairs = (unsigned*)scratch;                    // 12.8 MB
  int* PH = (int*)(scratch + ((size_t)13 << 20));          // G*NBK*PB*4 = 200KB
  int* POFF = (int*)(scratch + ((size_t)14 << 20));        // 200KB
  int* BB = (int*)(scratch + ((size_t)15 << 20));          // G*(NBK+1)*4 = 3.2KB
  ushort* xh = (ushort*)(scratch + ((size_t)32 << 20));    // fp16 x, 25.6 MB

  // 1. CSR build via two-pass radix partition (line-contiguous writes only)
  k_phist<<<dim3(PB, G), 256, 0, stream>>>(ei, PH);
  k_pscan<<<G, 256, 0, stream>>>(PH, POFF, BB);
  k_part<<<dim3(PB, G), 256, 0, stream>>>(ei, POFF, pairs);
  k_bcnt<<<dim3(NBK, G), 256, 0, stream>>>(pairs, BB, cnt);
  dim3 sg(NB, G);
  k_scan_partial<<<sg, 256, 0, stream>>>(cnt, part);
  k_scan_mid<<<G, 64, 0, stream>>>(part, rowptr);
  k_scan_final<<<sg, 256, 0, stream>>>(cnt, part, rowptr, dinv);
  k_place<<<dim3(NBK, G), 256, 0, stream>>>(pairs, BB, rowptr, col);

  // 2. x -> fp16 pre-scaled by dinv (after scans; removes per-edge dinv work)
  k_x2h<<<(G * N * FIN / 4 + 255) / 256, 256, 0, stream>>>(
      (const float4*)x, dinv, (ushort4*)xh, G * N * FIN / 4);

  // 3. layer 1 aggregate (16-deep scalar-index fp16 gathers)
  k_agg_in<FIN><<<(G * N) / 4, 256, 0, stream>>>(xh, rowptr, col, dinv, z);

  // 4. fused MLP: z -> (h1 fp16 in-LDS) -> h2s (pre-scaled fp16)
  dim3 gg((N + 63) / 64, G);
  k_mlp<<<gg, 256, 0, stream>>>(z, W1, b1, W2, dinv, h2s);

  // 5. layer 2 aggregate + bias + ELU
  k_agg_out<FOUT><<<(G * N) / 4, 256, 0, stream>>>(h2s, rowptr, col, dinv, b2, out);
}

// Round 11
// 463.809 us; speedup vs baseline: 1.0577x; 1.0577x over previous
//
#include <hip/hip_runtime.h>
#include <cstdint>

// Problem constants (from reference)
constexpr int G = 4, N = 50000, E = 800000;
constexpr int FIN = 64, HID = 128, FOUT = 64;
constexpr int NB = (N + 1023) / 1024;  // scan blocks per graph = 49

// Radix CSR-build parameters (R9)
constexpr int PB = 64;               // partition blocks per graph
constexpr int CP = E / PB;           // 12500 edges per partition chunk (exact)
constexpr int NBK = (N + 255) / 256; // 196 dst-buckets of 256 nodes

typedef unsigned short ushort;
typedef _Float16 f16;

__device__ __forceinline__ ushort f2h(float f) {  // v_cvt_f16_f32 (RNE)
  f16 h = (f16)f;
  return __builtin_bit_cast(ushort, h);
}
__device__ __forceinline__ float h2f(ushort u) {  // v_cvt_f32_f16
  f16 h = __builtin_bit_cast(f16, u);
  return (float)h;
}

// XCD-confined swizzle: block b -> XCD (b&7), 2 XCDs per graph.
// Requires G*N/4 = 50000 blocks; per graph 12500 chunks of 4 nodes.
__device__ __forceinline__ void xcd_map(int b, int& g, int& chunk) {
  int xcd = b & 7;
  int sub = b >> 3;  // 0..6249
  g = xcd >> 1;
  chunk = (xcd & 1) * 6250 + sub;  // 0..12499
}

// ---------------- fp32 -> fp16 conversion of x, PRE-SCALED by dinv ----------------
// R7: fp16 halves gather bytes + L2 working set. R10: also fold dinv[s] into
// the stored row (xh[s] = dinv[s]*x[s]) so the aggregation needs NO per-edge
// dinv gather -- Z = dinv[d] * sum_{s in N(d)+self} xh[s]. Runs AFTER the scans.
__global__ void k_x2h(const float4* __restrict__ X, const float* __restrict__ dinv,
                      ushort4* __restrict__ Xh, int n4) {
  int i = blockIdx.x * blockDim.x + threadIdx.x;
  if (i >= n4) return;
  float sc = dinv[i >> 4];  // 16 float4 per 64-wide row; same dinv for all 16
  float4 v = X[i];
  ushort4 o = {f2h(sc * v.x), f2h(sc * v.y), f2h(sc * v.z), f2h(sc * v.w)};
  Xh[i] = o;
}

// ---------------- CSR build: two-pass radix partition by dst (R9) ----------------
// R8 post-mortem: scattered SUB-LINE stores cost like atomics (8x write amp).
// All global writes made (near-)line-contiguous via 196-bucket dst partition.

// PH[g][k][pb]: bucket-k count of partition chunk pb
__global__ __launch_bounds__(256) void k_phist(const int* __restrict__ ei,
                                               int* __restrict__ PH) {
  __shared__ int h[NBK];
  int pb = blockIdx.x, g = blockIdx.y;
  for (int i = threadIdx.x; i < NBK; i += 256) h[i] = 0;
  __syncthreads();
  const int4* dst4 = (const int4*)(ei + (size_t)g * 2 * E + E + (size_t)pb * CP);
  for (int i = threadIdx.x; i < CP / 4; i += 256) {
    int4 d = dst4[i];
    atomicAdd(&h[d.x >> 8], 1);
    atomicAdd(&h[d.y >> 8], 1);
    atomicAdd(&h[d.z >> 8], 1);
    atomicAdd(&h[d.w >> 8], 1);
  }
  __syncthreads();
  for (int i = threadIdx.x; i < NBK; i += 256)
    PH[((size_t)g * NBK + i) * PB + pb] = h[i];
}

// scan PH -> POFF[g][k][pb] (segment base in pairs) and BB[g][k] (bucket base)
__global__ void k_pscan(const int* __restrict__ PH, int* __restrict__ POFF,
                        int* __restrict__ BB) {
  int g = blockIdx.x, k = threadIdx.x;  // 256 threads, k < NBK active
  int tot = 0;
  if (k < NBK) {
#pragma unroll 8
    for (int pb = 0; pb < PB; ++pb) tot += PH[((size_t)g * NBK + k) * PB + pb];
  }
  __shared__ int sm[256];
  sm[k] = tot;
  __syncthreads();
  for (int off = 1; off < 256; off <<= 1) {
    int v = (k >= off) ? sm[k - off] : 0;
    __syncthreads();
    sm[k] += v;
    __syncthreads();
  }
  int excl = sm[k] - tot;
  if (k < NBK) {
    BB[g * (NBK + 1) + k] = excl;
    if (k == NBK - 1) BB[g * (NBK + 1) + NBK] = excl + tot;  // == E
    int run = excl;
#pragma unroll 8
    for (int pb = 0; pb < PB; ++pb) {
      POFF[((size_t)g * NBK + k) * PB + pb] = run;
      run += PH[((size_t)g * NBK + k) * PB + pb];
    }
  }
}

// partition: write packed (src, dst&255) into bucket-major pairs array
__global__ __launch_bounds__(256) void k_part(const int* __restrict__ ei,
                                              const int* __restrict__ POFF,
                                              unsigned* __restrict__ pairs) {
  __shared__ int off[NBK];
  __shared__ int rk[NBK];
  int pb = blockIdx.x, g = blockIdx.y;
  for (int i = threadIdx.x; i < NBK; i += 256) {
    off[i] = POFF[((size_t)g * NBK + i) * PB + pb];
    rk[i] = 0;
  }
  __syncthreads();
  const int* base = ei + (size_t)g * 2 * E + (size_t)pb * CP;
  const int4* s4 = (const int4*)base;
  const int4* d4 = (const int4*)(base + E);
  unsigned* pg = pairs + (size_t)g * E;
  for (int i = threadIdx.x; i < CP / 4; i += 256) {
    int4 s = s4[i], d = d4[i];
    int sv[4] = {s.x, s.y, s.z, s.w};
    int dv[4] = {d.x, d.y, d.z, d.w};
#pragma unroll
    for (int k = 0; k < 4; ++k) {
      int b = dv[k] >> 8;
      int r = atomicAdd(&rk[b], 1);
      pg[off[b] + r] = (unsigned)sv[k] | ((unsigned)(dv[k] & 255) << 16);
    }
  }
}

// per-bucket exact node counts -> cnt (contiguous writes)
__global__ __launch_bounds__(256) void k_bcnt(const unsigned* __restrict__ pairs,
                                              const int* __restrict__ BB,
                                              int* __restrict__ cnt) {
  __shared__ int h[256];
  int k = blockIdx.x, g = blockIdx.y;
  h[threadIdx.x] = 0;
  __syncthreads();
  int lo = BB[g * (NBK + 1) + k], hi = BB[g * (NBK + 1) + k + 1];
  const unsigned* pg = pairs + (size_t)g * E;
  for (int i = lo + (int)threadIdx.x; i < hi; i += 256)
    atomicAdd(&h[(pg[i] >> 16) & 255], 1);
  __syncthreads();
  int n0 = k << 8;
  int nn = min(256, N - n0);
  if ((int)threadIdx.x < nn) cnt[g * N + n0 + threadIdx.x] = h[threadIdx.x];
}

// place srcs into col; scatter confined to the bucket's ~16KB col window
__global__ __launch_bounds__(256) void k_place(const unsigned* __restrict__ pairs,
                                               const int* __restrict__ BB,
                                               const int* __restrict__ rowptr,
                                               int* __restrict__ col) {
  __shared__ int rp[256];
  __shared__ int rk[256];
  int k = blockIdx.x, g = blockIdx.y;
  int n0 = k << 8;
  int nn = min(256, N - n0);
  if ((int)threadIdx.x < nn) rp[threadIdx.x] = rowptr[g * (N + 1) + n0 + threadIdx.x];
  rk[threadIdx.x] = 0;
  __syncthreads();
  int lo = BB[g * (NBK + 1) + k], hi = BB[g * (NBK + 1) + k + 1];
  const unsigned* pg = pairs + (size_t)g * E;
  int* cg = col + (size_t)g * E;
  for (int i = lo + (int)threadIdx.x; i < hi; i += 256) {
    unsigned p = pg[i];
    int dl = (p >> 16) & 255;
    int r = atomicAdd(&rk[dl], 1);
    cg[rp[dl] + r] = (int)(p & 0xffffu);
  }
}

// ---- 3-kernel exclusive scan of cnt -> rowptr (per graph) ----
__global__ void k_scan_partial(const int* __restrict__ cnt, int* __restrict__ part) {
  int g = blockIdx.y, b = blockIdx.x, tid = threadIdx.x;
  int base = b * 1024 + tid * 4;
  int s = 0;
#pragma unroll
  for (int k = 0; k < 4; ++k) {
    int i = base + k;
    if (i < N) s += cnt[g * N + i];
  }
  __shared__ int sm[256];
  sm[tid] = s;
  __syncthreads();
  for (int off = 128; off > 0; off >>= 1) {
    if (tid < off) sm[tid] += sm[tid + off];
    __syncthreads();
  }
  if (tid == 0) part[g * NB + b] = sm[0];
}

__global__ void k_scan_mid(int* __restrict__ part, int* __restrict__ rowptr) {
  int g = blockIdx.x;
  if (threadIdx.x != 0) return;
  int run = 0;
  for (int b = 0; b < NB; ++b) {
    int t = part[g * NB + b];
    part[g * NB + b] = run;
    run += t;
  }
  rowptr[g * (N + 1) + N] = run;  // == E
}

// final scan + fused dinv computation
__global__ void k_scan_final(const int* __restrict__ cnt, const int* __restrict__ part,
                             int* __restrict__ rowptr, float* __restrict__ dinv) {
  int g = blockIdx.y, b = blockIdx.x, tid = threadIdx.x;
  int base = b * 1024 + tid * 4;
  int c[4];
  int s = 0;
#pragma unroll
  for (int k = 0; k < 4; ++k) {
    int i = base + k;
    c[k] = (i < N) ? cnt[g * N + i] : 0;
    s += c[k];
  }
  __shared__ int sm[256];
  sm[tid] = s;
  __syncthreads();
  for (int off = 1; off < 256; off <<= 1) {
    int v = (tid >= off) ? sm[tid - off] : 0;
    __syncthreads();
    sm[tid] += v;
    __syncthreads();
  }
  int excl = sm[tid] - s + part[g * NB + b];
#pragma unroll
  for (int k = 0; k < 4; ++k) {
    int i = base + k;
    if (i < N) {
      rowptr[g * (N + 1) + i] = excl;
      dinv[g * N + i] = rsqrtf((float)(c[k] + 1));  // +1 self loop
    }
    excl += c[k];
  }
}

// ---------------- fused MLP: h2s = dinv * (ELU(Z@W1 + b1) @ W2), fp16 out ----------------
// R14 structure: gemm1 k-slices written to LDS as PACKED FP16 h1 [64][130]
// (16.64KB == x-tile size -> union buffer), gemm2 reads full h1 rows (wave w
// computes cols [16w,16w+16), lane=row). 3 barriers, no cross-wave reduce.
// R15: R14's __launch_bounds__(256,8) pinned VGPR to 64 and the allocator
// SPILLED acc[32] (VGPR_Count=20 -- impossible for a live fp32 acc[32];
// spill moves cost +12% despite occupancy 38->70%). Plain (256) lets the
// allocator take its natural ~52-64 VGPR (cf. k_gemm_lds: 52, no spill);
// at <=64 VGPR the 8-waves/SIMD occupancy survives anyway.
// W1/W2 addresses scalar (readfirstlane) -> constant-cache s_load (R5 lesson).
// h1s bank map: dword idx = row*65 + c/2 -> (row + c/2)%32, 2 lanes/bank, free.
__global__ __launch_bounds__(256) void k_mlp(const float* __restrict__ X,
                                             const float* __restrict__ W1,
                                             const float* __restrict__ b1,
                                             const float* __restrict__ W2,
                                             const float* __restrict__ dinv,
                                             ushort* __restrict__ H2s) {
  constexpr int K = FIN;     // 64
  constexpr int PK = K + 1;  // padded x-tile row stride
  __shared__ float lds[64 * PK];        // 16640B; aliased as fp16 h1 [64][130]
  ushort* h1s = (ushort*)lds;
  int g = blockIdx.y;
  int R0 = blockIdx.x * 64;
  // stage 64 rows of Z (coalesced global read, conflict-free LDS write)
  for (int idx = threadIdx.x; idx < 64 * K; idx += 256) {
    int r = idx >> 6, k = idx & 63;
    int row = R0 + r;
    lds[r * PK + k] = (row < N) ? X[((size_t)g * N + row) * K + k] : 0.f;
  }
  __syncthreads();
  int wv = threadIdx.x >> 6;
  int lane = threadIdx.x & 63;
  int c0 = __builtin_amdgcn_readfirstlane(wv * 32);  // SGPR col base (HID slice)
  const float* W1g = W1 + (size_t)g * K * HID;
  const float* xrow = &lds[lane * PK];
  float acc[32];
#pragma unroll
  for (int c = 0; c < 32; ++c) acc[c] = 0.f;
#pragma unroll 4
  for (int k = 0; k < K; ++k) {
    float xv = xrow[k];
#pragma unroll
    for (int c = 0; c < 32; ++c)
      acc[c] = fmaf(xv, W1g[(size_t)k * HID + c0 + c], acc[c]);
  }
  // bias + ELU -> acc = h1[row][c0..c0+31]
#pragma unroll
  for (int c = 0; c < 32; ++c) {
    float v = acc[c] + b1[g * HID + c0 + c];
    acc[c] = v > 0.f ? v : expm1f(v);
  }
  __syncthreads();  // all x-tile reads complete before h1 overwrites the buffer
  // write h1 slice as packed fp16 (dword-aligned, 2-lanes/bank)
#pragma unroll
  for (int c2 = 0; c2 < 16; ++c2) {
    unsigned pk = (unsigned)f2h(acc[2 * c2]) | ((unsigned)f2h(acc[2 * c2 + 1]) << 16);
    *(unsigned*)&h1s[lane * 130 + c0 + 2 * c2] = pk;
  }
  __syncthreads();
  // gemm2: wave w computes output cols [16w, 16w+16) for all 64 rows (lane=row)
  int j0 = __builtin_amdgcn_readfirstlane(wv * 16);
  const float* W2g = W2 + (size_t)g * HID * FOUT + j0;
  float acc2[16];
#pragma unroll
  for (int j = 0; j < 16; ++j) acc2[j] = 0.f;
#pragma unroll 4
  for (int c = 0; c < HID; c += 2) {
    unsigned pk = *(const unsigned*)&h1s[lane * 130 + c];
    float f0 = h2f((ushort)(pk & 0xffffu));
    float f1 = h2f((ushort)(pk >> 16));
    const float* w0 = &W2g[(size_t)c * FOUT];
    const float* w1 = &W2g[(size_t)(c + 1) * FOUT];
#pragma unroll
    for (int j = 0; j < 16; ++j) acc2[j] = fmaf(f0, w0[j], acc2[j]);
#pragma unroll
    for (int j = 0; j < 16; ++j) acc2[j] = fmaf(f1, w1[j], acc2[j]);
  }
  int row = R0 + lane;
  if (row < N) {
    float dd = dinv[g * N + row];
    ushort o[16];
#pragma unroll
    for (int j = 0; j < 16; ++j) o[j] = f2h(acc2[j] * dd);
    ushort* dst = H2s + ((size_t)g * N + row) * FOUT + j0;
    *(uint4*)dst = *(uint4*)&o[0];        // 16B aligned: (row*128 + j0*2) % 16 == 0
    *(uint4*)(dst + 8) = *(uint4*)&o[8];
  }
}

// ---------------- aggregate core (R12) ----------------
// R11 post-mortem: quarter-wave ushort4 gathers REGRESSED -- shfl epilogue
// added 17.9M LDS bank-conflict cycles. R12: R10 scalar-index structure,
// 16-deep primary batch, 8-deep secondary, scalar tail. ~89us floor = TA/
// line-processing bound (2 lines per 128B row-gather), invariant to MLP.
__device__ __forceinline__ float agg_row(const ushort* __restrict__ hb,
                                         const int* __restrict__ cl, int rs, int re,
                                         int lane, float acc) {
  int j = rs;
  for (; j + 16 <= re; j += 16) {
    int s[16];
#pragma unroll
    for (int k = 0; k < 16; ++k) s[k] = cl[j + k];  // uniform -> s_load x16
    float v[16];
#pragma unroll
    for (int k = 0; k < 16; ++k) v[k] = h2f(hb[(size_t)s[k] * 64 + lane]);
#pragma unroll
    for (int k = 0; k < 16; ++k) acc += v[k];
  }
  for (; j + 8 <= re; j += 8) {
    int s[8];
#pragma unroll
    for (int k = 0; k < 8; ++k) s[k] = cl[j + k];
    float v[8];
#pragma unroll
    for (int k = 0; k < 8; ++k) v[k] = h2f(hb[(size_t)s[k] * 64 + lane]);
#pragma unroll
    for (int k = 0; k < 8; ++k) acc += v[k];
  }
  for (; j < re; ++j) acc += h2f(hb[(size_t)cl[j] * 64 + lane]);
  return acc;
}

// layer 1: Z = dinv[d] * sum xh[s] (xh pre-scaled by dinv[s])
template <int F>
__global__ __launch_bounds__(256) void k_agg_in(const ushort* __restrict__ Xh,
                                                const int* __restrict__ rowptr,
                                                const int* __restrict__ col,
                                                const float* __restrict__ dinv,
                                                float* __restrict__ Z) {
  int g, chunk;
  xcd_map(blockIdx.x, g, chunk);
  int d = __builtin_amdgcn_readfirstlane(chunk * 4 + (threadIdx.x >> 6));
  int lane = threadIdx.x & 63;
  const ushort* hb = Xh + (size_t)g * N * F;
  const int* cl = col + (size_t)g * E;
  int rs = rowptr[g * (N + 1) + d];
  int re = rowptr[g * (N + 1) + d + 1];
  float acc = h2f(hb[(size_t)d * F + lane]);  // self loop (pre-scaled row)
  acc = agg_row(hb, cl, rs, re, lane, acc);
  Z[((size_t)g * N + d) * F + lane] = dinv[g * N + d] * acc;
}

// layer 2: out = ELU(dinv[d]*(sum h2s) + b); h2s pre-scaled by dinv[s]
template <int F>
__global__ __launch_bounds__(256) void k_agg_out(const ushort* __restrict__ Hsrc,
                                                 const int* __restrict__ rowptr,
                                                 const int* __restrict__ col,
                                                 const float* __restrict__ dinv,
                                                 const float* __restrict__ bias,
                                                 float* __restrict__ out) {
  int g, chunk;
  xcd_map(blockIdx.x, g, chunk);
  int d = __builtin_amdgcn_readfirstlane(chunk * 4 + (threadIdx.x >> 6));
  int lane = threadIdx.x & 63;
  const ushort* hb = Hsrc + (size_t)g * N * F;
  const int* cl = col + (size_t)g * E;
  int rs = rowptr[g * (N + 1) + d];
  int re = rowptr[g * (N + 1) + d + 1];
  float acc = h2f(hb[(size_t)d * F + lane]);  // self loop
  acc = agg_row(hb, cl, rs, re, lane, acc);
  float p = acc * dinv[g * N + d] + bias[g * F + lane];
  p = p > 0.f ? p : expm1f(p);
  out[((size_t)g * N + d) * F + lane] = p;
}

extern "C" void kernel_launch(void* const* d_in, const int* in_sizes, int n_in,
                              void* d_out, int out_size, void* d_ws, size_t ws_size,
                              hipStream_t stream) {
  const float* x = (const float*)d_in[0];
  const int* ei = (const int*)d_in[1];
  const float* W1 = (const float*)d_in[2];
  const float* b1 = (const float*)d_in[3];
  const float* W2 = (const float*)d_in[4];
  const float* b2 = (const float*)d_in[5];
  float* out = (float*)d_out;

  // Workspace carve-up (layout kept from R9; h1's region now only holds the
  // radix + fp16-x scratch -- h1 itself no longer exists, R13 fused it away)
  char* p = (char*)d_ws;
  auto alloc = [&](size_t bytes) {
    char* r = p;
    p += (bytes + 255) & ~(size_t)255;
    return r;
  };
  int* cnt = (int*)alloc(sizeof(int) * G * N);
  int* rowptr = (int*)alloc(sizeof(int) * G * (N + 1));
  int* part = (int*)alloc(sizeof(int) * G * NB);
  float* dinv = (float*)alloc(sizeof(float) * G * N);
  int* col = (int*)alloc(sizeof(int) * (size_t)G * E);             // 12.8 MB
  float* z = (float*)alloc(sizeof(float) * (size_t)G * N * FIN);   // 51.2 MB
  char* scratch = (char*)alloc((size_t)103 << 20);                 // ex-h1 region
  ushort* h2s = (ushort*)z;  // fp16, 25.6 MB; reuses z (dead after k_mlp reads it)
  unsigned* pairs = (unsigned*)scratch;                    // 12.8 MB
  int* PH = (int*)(scratch + ((size_t)13 << 20));          // G*NBK*PB*4 = 200KB
  int* POFF = (int*)(scratch + ((size_t)14 << 20));        // 200KB
  int* BB = (int*)(scratch + ((size_t)15 << 20));          // G*(NBK+1)*4 = 3.2KB
  ushort* xh = (ushort*)(scratch + ((size_t)32 << 20));    // fp16 x, 25.6 MB

  // 1. CSR build via two-pass radix partition (line-contiguous writes only)
  k_phist<<<dim3(PB, G), 256, 0, stream>>>(ei, PH);
  k_pscan<<<G, 256, 0, stream>>>(PH, POFF, BB);
  k_part<<<dim3(PB, G), 256, 0, stream>>>(ei, POFF, pairs);
  k_bcnt<<<dim3(NBK, G), 256, 0, stream>>>(pairs, BB, cnt);
  dim3 sg(NB, G);
  k_scan_partial<<<sg, 256, 0, stream>>>(cnt, part);
  k_scan_mid<<<G, 64, 0, stream>>>(part, rowptr);
  k_scan_final<<<sg, 256, 0, stream>>>(cnt, part, rowptr, dinv);
  k_place<<<dim3(NBK, G), 256, 0, stream>>>(pairs, BB, rowptr, col);

  // 2. x -> fp16 pre-scaled by dinv (after scans; removes per-edge dinv work)
  k_x2h<<<(G * N * FIN / 4 + 255) / 256, 256, 0, stream>>>(
      (const float4*)x, dinv, (ushort4*)xh, G * N * FIN / 4);

  // 3. layer 1 aggregate (16-deep scalar-index fp16 gathers)
  k_agg_in<FIN><<<(G * N) / 4, 256, 0, stream>>>(xh, rowptr, col, dinv, z);

  // 4. fused MLP: z -> (h1 fp16 in-LDS) -> h2s (pre-scaled fp16)
  dim3 gg((N + 63) / 64, G);
  k_mlp<<<gg, 256, 0, stream>>>(z, W1, b1, W2, dinv, h2s);

  // 5. layer 2 aggregate + bias + ELU
  k_agg_out<FOUT><<<(G * N) / 4, 256, 0, stream>>>(h2s, rowptr, col, dinv, b2, out);
}

// Round 12
// 445.500 us; speedup vs baseline: 1.1012x; 1.0411x over previous
//
#include <hip/hip_runtime.h>
#include <cstdint>

// Problem constants (from reference)
constexpr int G = 4, N = 50000, E = 800000;
constexpr int FIN = 64, HID = 128, FOUT = 64;
constexpr int NB = (N + 1023) / 1024;  // scan blocks per graph = 49

// Radix CSR-build parameters (R9)
constexpr int PB = 64;               // partition blocks per graph
constexpr int CP = E / PB;           // 12500 edges per partition chunk (exact)
constexpr int NBK = (N + 255) / 256; // 196 dst-buckets of 256 nodes

// Fused layer-1 tiling (R16)
constexpr int NT = (N + 63) / 64;    // 782 row-tiles per graph
constexpr int NTH = 391;             // tiles per half-XCD pair (782/2)

typedef unsigned short ushort;
typedef _Float16 f16;

__device__ __forceinline__ ushort f2h(float f) {  // v_cvt_f16_f32 (RNE)
  f16 h = (f16)f;
  return __builtin_bit_cast(ushort, h);
}
__device__ __forceinline__ float h2f(ushort u) {  // v_cvt_f32_f16
  f16 h = __builtin_bit_cast(f16, u);
  return (float)h;
}

// XCD-confined swizzle: block b -> XCD (b&7), 2 XCDs per graph.
// Requires G*N/4 = 50000 blocks; per graph 12500 chunks of 4 nodes.
__device__ __forceinline__ void xcd_map(int b, int& g, int& chunk) {
  int xcd = b & 7;
  int sub = b >> 3;  // 0..6249
  g = xcd >> 1;
  chunk = (xcd & 1) * 6250 + sub;  // 0..12499
}

// ---------------- fp32 -> fp16 conversion of x, PRE-SCALED by dinv ----------------
// R7: fp16 halves gather bytes + L2 working set. R10: also fold dinv[s] into
// the stored row (xh[s] = dinv[s]*x[s]) so the aggregation needs NO per-edge
// dinv gather -- Z = dinv[d] * sum_{s in N(d)+self} xh[s]. Runs AFTER the scans.
__global__ void k_x2h(const float4* __restrict__ X, const float* __restrict__ dinv,
                      ushort4* __restrict__ Xh, int n4) {
  int i = blockIdx.x * blockDim.x + threadIdx.x;
  if (i >= n4) return;
  float sc = dinv[i >> 4];  // 16 float4 per 64-wide row; same dinv for all 16
  float4 v = X[i];
  ushort4 o = {f2h(sc * v.x), f2h(sc * v.y), f2h(sc * v.z), f2h(sc * v.w)};
  Xh[i] = o;
}

// ---------------- CSR build: two-pass radix partition by dst (R9) ----------------
// R8 post-mortem: scattered SUB-LINE stores cost like atomics (8x write amp).
// All global writes made (near-)line-contiguous via 196-bucket dst partition.

// PH[g][k][pb]: bucket-k count of partition chunk pb
__global__ __launch_bounds__(256) void k_phist(const int* __restrict__ ei,
                                               int* __restrict__ PH) {
  __shared__ int h[NBK];
  int pb = blockIdx.x, g = blockIdx.y;
  for (int i = threadIdx.x; i < NBK; i += 256) h[i] = 0;
  __syncthreads();
  const int4* dst4 = (const int4*)(ei + (size_t)g * 2 * E + E + (size_t)pb * CP);
  for (int i = threadIdx.x; i < CP / 4; i += 256) {
    int4 d = dst4[i];
    atomicAdd(&h[d.x >> 8], 1);
    atomicAdd(&h[d.y >> 8], 1);
    atomicAdd(&h[d.z >> 8], 1);
    atomicAdd(&h[d.w >> 8], 1);
  }
  __syncthreads();
  for (int i = threadIdx.x; i < NBK; i += 256)
    PH[((size_t)g * NBK + i) * PB + pb] = h[i];
}

// scan PH -> POFF[g][k][pb] (segment base in pairs) and BB[g][k] (bucket base)
__global__ void k_pscan(const int* __restrict__ PH, int* __restrict__ POFF,
                        int* __restrict__ BB) {
  int g = blockIdx.x, k = threadIdx.x;  // 256 threads, k < NBK active
  int tot = 0;
  if (k < NBK) {
#pragma unroll 8
    for (int pb = 0; pb < PB; ++pb) tot += PH[((size_t)g * NBK + k) * PB + pb];
  }
  __shared__ int sm[256];
  sm[k] = tot;
  __syncthreads();
  for (int off = 1; off < 256; off <<= 1) {
    int v = (k >= off) ? sm[k - off] : 0;
    __syncthreads();
    sm[k] += v;
    __syncthreads();
  }
  int excl = sm[k] - tot;
  if (k < NBK) {
    BB[g * (NBK + 1) + k] = excl;
    if (k == NBK - 1) BB[g * (NBK + 1) + NBK] = excl + tot;  // == E
    int run = excl;
#pragma unroll 8
    for (int pb = 0; pb < PB; ++pb) {
      POFF[((size_t)g * NBK + k) * PB + pb] = run;
      run += PH[((size_t)g * NBK + k) * PB + pb];
    }
  }
}

// partition: write packed (src, dst&255) into bucket-major pairs array
__global__ __launch_bounds__(256) void k_part(const int* __restrict__ ei,
                                              const int* __restrict__ POFF,
                                              unsigned* __restrict__ pairs) {
  __shared__ int off[NBK];
  __shared__ int rk[NBK];
  int pb = blockIdx.x, g = blockIdx.y;
  for (int i = threadIdx.x; i < NBK; i += 256) {
    off[i] = POFF[((size_t)g * NBK + i) * PB + pb];
    rk[i] = 0;
  }
  __syncthreads();
  const int* base = ei + (size_t)g * 2 * E + (size_t)pb * CP;
  const int4* s4 = (const int4*)base;
  const int4* d4 = (const int4*)(base + E);
  unsigned* pg = pairs + (size_t)g * E;
  for (int i = threadIdx.x; i < CP / 4; i += 256) {
    int4 s = s4[i], d = d4[i];
    int sv[4] = {s.x, s.y, s.z, s.w};
    int dv[4] = {d.x, d.y, d.z, d.w};
#pragma unroll
    for (int k = 0; k < 4; ++k) {
      int b = dv[k] >> 8;
      int r = atomicAdd(&rk[b], 1);
      pg[off[b] + r] = (unsigned)sv[k] | ((unsigned)(dv[k] & 255) << 16);
    }
  }
}

// per-bucket exact node counts -> cnt (contiguous writes)
__global__ __launch_bounds__(256) void k_bcnt(const unsigned* __restrict__ pairs,
                                              const int* __restrict__ BB,
                                              int* __restrict__ cnt) {
  __shared__ int h[256];
  int k = blockIdx.x, g = blockIdx.y;
  h[threadIdx.x] = 0;
  __syncthreads();
  int lo = BB[g * (NBK + 1) + k], hi = BB[g * (NBK + 1) + k + 1];
  const unsigned* pg = pairs + (size_t)g * E;
  for (int i = lo + (int)threadIdx.x; i < hi; i += 256)
    atomicAdd(&h[(pg[i] >> 16) & 255], 1);
  __syncthreads();
  int n0 = k << 8;
  int nn = min(256, N - n0);
  if ((int)threadIdx.x < nn) cnt[g * N + n0 + threadIdx.x] = h[threadIdx.x];
}

// place srcs into col; scatter confined to the bucket's ~16KB col window
__global__ __launch_bounds__(256) void k_place(const unsigned* __restrict__ pairs,
                                               const int* __restrict__ BB,
                                               const int* __restrict__ rowptr,
                                               int* __restrict__ col) {
  __shared__ int rp[256];
  __shared__ int rk[256];
  int k = blockIdx.x, g = blockIdx.y;
  int n0 = k << 8;
  int nn = min(256, N - n0);
  if ((int)threadIdx.x < nn) rp[threadIdx.x] = rowptr[g * (N + 1) + n0 + threadIdx.x];
  rk[threadIdx.x] = 0;
  __syncthreads();
  int lo = BB[g * (NBK + 1) + k], hi = BB[g * (NBK + 1) + k + 1];
  const unsigned* pg = pairs + (size_t)g * E;
  int* cg = col + (size_t)g * E;
  for (int i = lo + (int)threadIdx.x; i < hi; i += 256) {
    unsigned p = pg[i];
    int dl = (p >> 16) & 255;
    int r = atomicAdd(&rk[dl], 1);
    cg[rp[dl] + r] = (int)(p & 0xffffu);
  }
}

// ---- 3-kernel exclusive scan of cnt -> rowptr (per graph) ----
__global__ void k_scan_partial(const int* __restrict__ cnt, int* __restrict__ part) {
  int g = blockIdx.y, b = blockIdx.x, tid = threadIdx.x;
  int base = b * 1024 + tid * 4;
  int s = 0;
#pragma unroll
  for (int k = 0; k < 4; ++k) {
    int i = base + k;
    if (i < N) s += cnt[g * N + i];
  }
  __shared__ int sm[256];
  sm[tid] = s;
  __syncthreads();
  for (int off = 128; off > 0; off >>= 1) {
    if (tid < off) sm[tid] += sm[tid + off];
    __syncthreads();
  }
  if (tid == 0) part[g * NB + b] = sm[0];
}

__global__ void k_scan_mid(int* __restrict__ part, int* __restrict__ rowptr) {
  int g = blockIdx.x;
  if (threadIdx.x != 0) return;
  int run = 0;
  for (int b = 0; b < NB; ++b) {
    int t = part[g * NB + b];
    part[g * NB + b] = run;
    run += t;
  }
  rowptr[g * (N + 1) + N] = run;  // == E
}

// final scan + fused dinv computation
__global__ void k_scan_final(const int* __restrict__ cnt, const int* __restrict__ part,
                             int* __restrict__ rowptr, float* __restrict__ dinv) {
  int g = blockIdx.y, b = blockIdx.x, tid = threadIdx.x;
  int base = b * 1024 + tid * 4;
  int c[4];
  int s = 0;
#pragma unroll
  for (int k = 0; k < 4; ++k) {
    int i = base + k;
    c[k] = (i < N) ? cnt[g * N + i] : 0;
    s += c[k];
  }
  __shared__ int sm[256];
  sm[tid] = s;
  __syncthreads();
  for (int off = 1; off < 256; off <<= 1) {
    int v = (tid >= off) ? sm[tid - off] : 0;
    __syncthreads();
    sm[tid] += v;
    __syncthreads();
  }
  int excl = sm[tid] - s + part[g * NB + b];
#pragma unroll
  for (int k = 0; k < 4; ++k) {
    int i = base + k;
    if (i < N) {
      rowptr[g * (N + 1) + i] = excl;
      dinv[g * N + i] = rsqrtf((float)(c[k] + 1));  // +1 self loop
    }
    excl += c[k];
  }
}

// ---------------- aggregate core (R12) ----------------
// R11 post-mortem: quarter-wave ushort4 gathers REGRESSED -- shfl epilogue
// added 17.9M LDS bank-conflict cycles. R12: R10 scalar-index structure,
// 16-deep primary batch, 8-deep secondary, scalar tail. ~89us floor = gather-
// path bound (line processing), invariant to per-instr packing and MLP depth.
__device__ __forceinline__ float agg_row(const ushort* __restrict__ hb,
                                         const int* __restrict__ cl, int rs, int re,
                                         int lane, float acc) {
  int j = rs;
  for (; j + 16 <= re; j += 16) {
    int s[16];
#pragma unroll
    for (int k = 0; k < 16; ++k) s[k] = cl[j + k];  // uniform -> s_load x16
    float v[16];
#pragma unroll
    for (int k = 0; k < 16; ++k) v[k] = h2f(hb[(size_t)s[k] * 64 + lane]);
#pragma unroll
    for (int k = 0; k < 16; ++k) acc += v[k];
  }
  for (; j + 8 <= re; j += 8) {
    int s[8];
#pragma unroll
    for (int k = 0; k < 8; ++k) s[k] = cl[j + k];
    float v[8];
#pragma unroll
    for (int k = 0; k < 8; ++k) v[k] = h2f(hb[(size_t)s[k] * 64 + lane]);
#pragma unroll
    for (int k = 0; k < 8; ++k) acc += v[k];
  }
  for (; j < re; ++j) acc += h2f(hb[(size_t)cl[j] * 64 + lane]);
  return acc;
}

// ---------------- fused layer 1: agg_in + MLP (R16) ----------------
// R15 post-mortem: k_agg_in (89us, VALU 28%, memory-bound) and k_mlp (110us,
// VALU 64%, HBM 6%) ran back-to-back, each idling the other's pipe, linked by
// 100MB of z traffic. Fused: phase 1 aggregates 64 dst rows into the LDS
// x-tile (z never touches global); phases 2-3 are R15's verified gemm1 ->
// fp16-h1-in-LDS -> gemm2. Resident blocks at different phases co-schedule
// (m114 mechanism): gather latency hides under other blocks' FMA streams.
// 16.64KB LDS union buffer unchanged; flat 8*NTH grid keeps the XCD swizzle
// (graph -> 2-XCD L2 pair). Tail tile guarded (unguarded rowptr read past the
// array could yield a garbage-length edge loop).
__global__ __launch_bounds__(256) void k_l1(const ushort* __restrict__ Xh,
                                            const int* __restrict__ rowptr,
                                            const int* __restrict__ col,
                                            const float* __restrict__ dinv,
                                            const float* __restrict__ W1,
                                            const float* __restrict__ b1,
                                            const float* __restrict__ W2,
                                            ushort* __restrict__ H2s) {
  constexpr int PK = FIN + 1;  // 65: padded z-tile row stride
  __shared__ float lds[64 * PK];        // 16640B; aliased as fp16 h1 [64][130]
  ushort* h1s = (ushort*)lds;
  int b = blockIdx.x;
  int xcd = b & 7;
  int sub = b >> 3;                     // 0..NTH-1
  int g = xcd >> 1;
  int tile = (xcd & 1) * NTH + sub;     // 0..2*NTH-1 (= NT tiles, incl. tail)
  int R0 = tile * 64;
  int wv = threadIdx.x >> 6;
  int lane = threadIdx.x & 63;
  const ushort* hb = Xh + (size_t)g * N * FIN;
  const int* cl = col + (size_t)g * E;
  // phase 1: each wave aggregates 16 consecutive dst nodes (lane = feature)
  for (int i = 0; i < 16; ++i) {
    int d = __builtin_amdgcn_readfirstlane(R0 + wv * 16 + i);
    float zv = 0.f;
    if (d < N) {
      int rs = rowptr[g * (N + 1) + d];
      int re = rowptr[g * (N + 1) + d + 1];
      float acc = h2f(hb[(size_t)d * FIN + lane]);  // self loop (pre-scaled)
      acc = agg_row(hb, cl, rs, re, lane, acc);
      zv = dinv[g * N + d] * acc;
    }
    lds[(wv * 16 + i) * PK + lane] = zv;  // bank (row+lane)%32, conflict-free
  }
  __syncthreads();
  // phase 2: gemm1 -- wave w computes HID cols [32w,32w+32) for row=lane
  int c0 = __builtin_amdgcn_readfirstlane(wv * 32);  // SGPR col base
  const float* W1g = W1 + (size_t)g * FIN * HID;
  const float* xrow = &lds[lane * PK];
  float acc[32];
#pragma unroll
  for (int c = 0; c < 32; ++c) acc[c] = 0.f;
#pragma unroll 4
  for (int k = 0; k < FIN; ++k) {
    float xv = xrow[k];
#pragma unroll
    for (int c = 0; c < 32; ++c)
      acc[c] = fmaf(xv, W1g[(size_t)k * HID + c0 + c], acc[c]);
  }
#pragma unroll
  for (int c = 0; c < 32; ++c) {
    float v = acc[c] + b1[g * HID + c0 + c];
    acc[c] = v > 0.f ? v : expm1f(v);
  }
  __syncthreads();  // all z reads complete before h1 overwrites the buffer
#pragma unroll
  for (int c2 = 0; c2 < 16; ++c2) {
    unsigned pk = (unsigned)f2h(acc[2 * c2]) | ((unsigned)f2h(acc[2 * c2 + 1]) << 16);
    *(unsigned*)&h1s[lane * 130 + c0 + 2 * c2] = pk;
  }
  __syncthreads();
  // phase 3: gemm2 -- wave w computes output cols [16w,16w+16) for row=lane
  int j0 = __builtin_amdgcn_readfirstlane(wv * 16);
  const float* W2g = W2 + (size_t)g * HID * FOUT + j0;
  float acc2[16];
#pragma unroll
  for (int j = 0; j < 16; ++j) acc2[j] = 0.f;
#pragma unroll 4
  for (int c = 0; c < HID; c += 2) {
    unsigned pk = *(const unsigned*)&h1s[lane * 130 + c];
    float f0 = h2f((ushort)(pk & 0xffffu));
    float f1 = h2f((ushort)(pk >> 16));
    const float* w0 = &W2g[(size_t)c * FOUT];
    const float* w1 = &W2g[(size_t)(c + 1) * FOUT];
#pragma unroll
    for (int j = 0; j < 16; ++j) acc2[j] = fmaf(f0, w0[j], acc2[j]);
#pragma unroll
    for (int j = 0; j < 16; ++j) acc2[j] = fmaf(f1, w1[j], acc2[j]);
  }
  int row = R0 + lane;
  if (row < N) {
    float dd = dinv[g * N + row];
    ushort o[16];
#pragma unroll
    for (int j = 0; j < 16; ++j) o[j] = f2h(acc2[j] * dd);
    ushort* dst = H2s + ((size_t)g * N + row) * FOUT + j0;
    *(uint4*)dst = *(uint4*)&o[0];        // 16B aligned: (row*128 + j0*2) % 16 == 0
    *(uint4*)(dst + 8) = *(uint4*)&o[8];
  }
}

// layer 2: out = ELU(dinv[d]*(sum h2s) + b); h2s pre-scaled by dinv[s]
template <int F>
__global__ __launch_bounds__(256) void k_agg_out(const ushort* __restrict__ Hsrc,
                                                 const int* __restrict__ rowptr,
                                                 const int* __restrict__ col,
                                                 const float* __restrict__ dinv,
                                                 const float* __restrict__ bias,
                                                 float* __restrict__ out) {
  int g, chunk;
  xcd_map(blockIdx.x, g, chunk);
  int d = __builtin_amdgcn_readfirstlane(chunk * 4 + (threadIdx.x >> 6));
  int lane = threadIdx.x & 63;
  const ushort* hb = Hsrc + (size_t)g * N * F;
  const int* cl = col + (size_t)g * E;
  int rs = rowptr[g * (N + 1) + d];
  int re = rowptr[g * (N + 1) + d + 1];
  float acc = h2f(hb[(size_t)d * F + lane]);  // self loop
  acc = agg_row(hb, cl, rs, re, lane, acc);
  float p = acc * dinv[g * N + d] + bias[g * F + lane];
  p = p > 0.f ? p : expm1f(p);
  out[((size_t)g * N + d) * F + lane] = p;
}

extern "C" void kernel_launch(void* const* d_in, const int* in_sizes, int n_in,
                              void* d_out, int out_size, void* d_ws, size_t ws_size,
                              hipStream_t stream) {
  const float* x = (const float*)d_in[0];
  const int* ei = (const int*)d_in[1];
  const float* W1 = (const float*)d_in[2];
  const float* b1 = (const float*)d_in[3];
  const float* W2 = (const float*)d_in[4];
  const float* b2 = (const float*)d_in[5];
  float* out = (float*)d_out;

  // Workspace carve-up (z region retained; h2s aliases it. h1 gone since R13.)
  char* p = (char*)d_ws;
  auto alloc = [&](size_t bytes) {
    char* r = p;
    p += (bytes + 255) & ~(size_t)255;
    return r;
  };
  int* cnt = (int*)alloc(sizeof(int) * G * N);
  int* rowptr = (int*)alloc(sizeof(int) * G * (N + 1));
  int* part = (int*)alloc(sizeof(int) * G * NB);
  float* dinv = (float*)alloc(sizeof(float) * G * N);
  int* col = (int*)alloc(sizeof(int) * (size_t)G * E);             // 12.8 MB
  float* z = (float*)alloc(sizeof(float) * (size_t)G * N * FIN);   // 51.2 MB (h2s home)
  char* scratch = (char*)alloc((size_t)103 << 20);                 // radix + xh scratch
  ushort* h2s = (ushort*)z;  // fp16, 25.6 MB
  unsigned* pairs = (unsigned*)scratch;                    // 12.8 MB
  int* PH = (int*)(scratch + ((size_t)13 << 20));          // G*NBK*PB*4 = 200KB
  int* POFF = (int*)(scratch + ((size_t)14 << 20));        // 200KB
  int* BB = (int*)(scratch + ((size_t)15 << 20));          // G*(NBK+1)*4 = 3.2KB
  ushort* xh = (ushort*)(scratch + ((size_t)32 << 20));    // fp16 x, 25.6 MB

  // 1. CSR build via two-pass radix partition (line-contiguous writes only)
  k_phist<<<dim3(PB, G), 256, 0, stream>>>(ei, PH);
  k_pscan<<<G, 256, 0, stream>>>(PH, POFF, BB);
  k_part<<<dim3(PB, G), 256, 0, stream>>>(ei, POFF, pairs);
  k_bcnt<<<dim3(NBK, G), 256, 0, stream>>>(pairs, BB, cnt);
  dim3 sg(NB, G);
  k_scan_partial<<<sg, 256, 0, stream>>>(cnt, part);
  k_scan_mid<<<G, 64, 0, stream>>>(part, rowptr);
  k_scan_final<<<sg, 256, 0, stream>>>(cnt, part, rowptr, dinv);
  k_place<<<dim3(NBK, G), 256, 0, stream>>>(pairs, BB, rowptr, col);

  // 2. x -> fp16 pre-scaled by dinv (after scans; removes per-edge dinv work)
  k_x2h<<<(G * N * FIN / 4 + 255) / 256, 256, 0, stream>>>(
      (const float4*)x, dinv, (ushort4*)xh, G * N * FIN / 4);

  // 3. fused layer 1: aggregate (LDS z) -> gemm1 -> fp16 h1 (LDS) -> gemm2 -> h2s
  k_l1<<<8 * NTH, 256, 0, stream>>>(xh, rowptr, col, dinv, W1, b1, W2, h2s);

  // 4. layer 2 aggregate + bias + ELU
  k_agg_out<FOUT><<<(G * N) / 4, 256, 0, stream>>>(h2s, rowptr, col, dinv, b2, out);
}